// Round 9
// baseline (122.907 us; speedup 1.0000x reference)
//
#include <hip/hip_runtime.h>
#include <hip/hip_fp16.h>

// QDPPMixer, R9: R7 body (G=4 quad gather, fp16 table, DPP reduce,
// normalize-free algebra) with 1024-THREAD WORKGROUPS.
// Evidence: occupancy pinned at ~30% across R1-R8 regardless of VGPR count,
// WG count, loads-in-flight => consistent with a device-wide concurrent-WG
// tracking limit (~750-1000 WGs ~= 3000 waves ~= 11/CU at 256-thr WGs).
// 16 waves/WG raises waves-in-flight per tracked WG by 4x; VGPR (64) then
// allows up to 32 waves/CU. Single-variable change vs R7.

constexpr int   NA         = 8;
constexpr float Q_MIN      = -10.0f;
constexpr float Q_MAX      = 10.0f;
constexpr float NOISE_COEF = 0.1f;
constexpr float EPS        = 1e-8f;

typedef _Float16 half2_t __attribute__((ext_vector_type(2)));

__device__ __forceinline__ float dot2(half2_t a, half2_t b, float c) {
#if __has_builtin(__builtin_amdgcn_fdot2)
    return __builtin_amdgcn_fdot2(a, b, c, false);
#else
    return fmaf((float)a.x, (float)b.x, fmaf((float)a.y, (float)b.y, c));
#endif
}

// quad butterfly adds (pure VALU DPP)
__device__ __forceinline__ float qadd1(float x) {
    return x + __builtin_bit_cast(float,
        __builtin_amdgcn_mov_dpp(__builtin_bit_cast(int, x), 0xB1, 0xF, 0xF, true));
}
__device__ __forceinline__ float qadd2(float x) {
    return x + __builtin_bit_cast(float,
        __builtin_amdgcn_mov_dpp(__builtin_bit_cast(int, x), 0x4E, 0xF, 0xF, true));
}

// ---- convert W (8000x32 fp32) -> fp16, 4 floats/thread ----
__global__ __launch_bounds__(256) void convert_kernel(
    const float* __restrict__ W, __half* __restrict__ W16, int n4)
{
    int t = blockIdx.x * blockDim.x + threadIdx.x;
    if (t >= n4) return;
    float4 v = reinterpret_cast<const float4*>(W)[t];
    ushort4 h;
    h.x = __half_as_ushort(__float2half(v.x));
    h.y = __half_as_ushort(__float2half(v.y));
    h.z = __half_as_ushort(__float2half(v.z));
    h.w = __half_as_ushort(__float2half(v.w));
    reinterpret_cast<ushort4*>(W16)[t] = h;
}

__global__ __launch_bounds__(1024, 8) void qdpp_kernel(
    const float* __restrict__ agent_qs,
    const int*   __restrict__ states,
    const int*   __restrict__ actions,
    const float* __restrict__ noise,
    const __half* __restrict__ W16,   // (8000, 32) fp16, rows 64B
    float*       __restrict__ out,
    int bs)
{
    int tid = blockIdx.x * blockDim.x + threadIdx.x;
    int e = tid >> 2;        // element index (4 lanes per element)
    int l = tid & 3;         // lane in quad: halves [8l, 8l+8) of each row
    if (e >= bs) return;
    size_t base = (size_t)e * NA;

    // ---- indices (quad-broadcast loads) ----
    int4 s0 = *reinterpret_cast<const int4*>(states + base);
    int4 s1 = *reinterpret_cast<const int4*>(states + base + 4);
    int4 a0 = *reinterpret_cast<const int4*>(actions + base);
    int4 a1 = *reinterpret_cast<const int4*>(actions + base + 4);

    int lb = 8 * l;          // half-element offset within row
    int off[8];
    off[0] = (s0.x * 10 + a0.x        ) * 32 + lb;
    off[1] = (s0.y * 10 + a0.y + 1000 ) * 32 + lb;
    off[2] = (s0.z * 10 + a0.z + 2000 ) * 32 + lb;
    off[3] = (s0.w * 10 + a0.w + 3000 ) * 32 + lb;
    off[4] = (s1.x * 10 + a1.x + 4000 ) * 32 + lb;
    off[5] = (s1.y * 10 + a1.y + 5000 ) * 32 + lb;
    off[6] = (s1.z * 10 + a1.z + 6000 ) * 32 + lb;
    off[7] = (s1.w * 10 + a1.w + 7000 ) * 32 + lb;

    // ---- gather: ONE 16B instr per row; quad covers the whole 64B row ----
    uint4 raw[8];
    #pragma unroll
    for (int i = 0; i < 8; i++)
        raw[i] = *reinterpret_cast<const uint4*>(W16 + off[i]);

    // ---- streaming loads issued while gathers are in flight ----
    float4 qa = *reinterpret_cast<const float4*>(agent_qs + base);
    float4 qb = *reinterpret_cast<const float4*>(agent_qs + base + 4);
    float4 n0 = *reinterpret_cast<const float4*>(noise + base);
    float4 n1 = *reinterpret_cast<const float4*>(noise + base + 4);

    half2_t h[8][4];
    #pragma unroll
    for (int i = 0; i < 8; i++) {
        h[i][0] = __builtin_bit_cast(half2_t, raw[i].x);
        h[i][1] = __builtin_bit_cast(half2_t, raw[i].y);
        h[i][2] = __builtin_bit_cast(half2_t, raw[i].z);
        h[i][3] = __builtin_bit_cast(half2_t, raw[i].w);
    }

    // ---- per-lane partial Gram (this lane's 8 of 32 dims), v_dot2 chains ----
    float g[8][8];
    #pragma unroll
    for (int i = 0; i < 8; i++) {
        #pragma unroll
        for (int j = i; j < 8; j++) {
            float acc = dot2(h[i][0], h[j][0], 0.0f);
            acc = dot2(h[i][1], h[j][1], acc);
            acc = dot2(h[i][2], h[j][2], acc);
            acc = dot2(h[i][3], h[j][3], acc);
            g[i][j] = acc;
        }
    }

    // ---- quad butterfly reduce (pure VALU DPP) ----
    #pragma unroll
    for (int i = 0; i < 8; i++)
        #pragma unroll
        for (int j = i; j < 8; j++)
            g[i][j] = qadd2(qadd1(g[i][j]));

    // ---- Q-sum with clip ----
    float qsum = fminf(fmaxf(qa.x, Q_MIN), Q_MAX) + fminf(fmaxf(qa.y, Q_MIN), Q_MAX)
               + fminf(fmaxf(qa.z, Q_MIN), Q_MAX) + fminf(fmaxf(qa.w, Q_MIN), Q_MAX)
               + fminf(fmaxf(qb.x, Q_MIN), Q_MAX) + fminf(fmaxf(qb.y, Q_MIN), Q_MAX)
               + fminf(fmaxf(qb.z, Q_MIN), Q_MAX) + fminf(fmaxf(qb.w, Q_MIN), Q_MAX);

    float nz[8] = {n0.x, n0.y, n0.z, n0.w, n1.x, n1.y, n1.z, n1.w};

    // ---- Atil: off-diag = relu(g_ij), diag = g_ii*(1 + 0.1*nz_i + eps) ----
    float m[8][8];
    float pgii = 1.0f;
    #pragma unroll
    for (int i = 0; i < 8; i++) {
        pgii *= g[i][i];
        #pragma unroll
        for (int j = 0; j < 8; j++) {
            if (i == j) {
                m[i][i] = g[i][i] * fmaf(NOISE_COEF, nz[i], 1.0f + EPS);
            } else {
                float gij = (j > i) ? g[i][j] : g[j][i];   // compile-time select
                m[i][j] = fmaxf(gij, 0.0f);
            }
        }
    }

    // ---- det via unrolled no-pivot LU (diag-dominant in practice) ----
    float det = 1.0f;
    #pragma unroll
    for (int k = 0; k < 8; k++) {
        float p = m[k][k];
        det *= p;
        float ip = __builtin_amdgcn_rcpf(p);
        #pragma unroll
        for (int i = k + 1; i < 8; i++) {
            float f = m[i][k] * ip;
            #pragma unroll
            for (int j = k + 1; j < 8; j++)
                m[i][j] = fmaf(-f, m[k][j], m[i][j]);
        }
    }

    // det(M) = det(Atil)/prod(g_ii); out = qsum + log(det(M) + 1e-8)
    float detM = det * __builtin_amdgcn_rcpf(pgii);
    if (l == 0)
        out[e] = qsum + __logf(detM + EPS);
}

extern "C" void kernel_launch(void* const* d_in, const int* in_sizes, int n_in,
                              void* d_out, int out_size, void* d_ws, size_t ws_size,
                              hipStream_t stream) {
    const float* agent_qs = (const float*)d_in[0];
    const int*   states   = (const int*)d_in[1];
    const int*   actions  = (const int*)d_in[2];
    const float* noise    = (const float*)d_in[3];
    const float* W        = (const float*)d_in[4];
    float*       out      = (float*)d_out;
    __half*      W16      = (__half*)d_ws;          // 256000 halves = 512 KB

    int wn = in_sizes[4];             // 256000 floats
    int n4 = wn / 4;
    convert_kernel<<<(n4 + 255) / 256, 256, 0, stream>>>(W, W16, n4);

    int bs = in_sizes[0] / NA;            // 262144
    const int block = 1024;               // 16 waves per WG (the experiment)
    long long total = (long long)bs * 4;  // 4 lanes per element
    int grid = (int)((total + block - 1) / block);   // 1024 WGs
    qdpp_kernel<<<grid, block, 0, stream>>>(agent_qs, states, actions, noise, W16, out, bs);
}

// Round 10
// 96.097 us; speedup vs baseline: 1.2790x; 1.2790x over previous
//
#include <hip/hip_runtime.h>
#include <hip/hip_fp16.h>

// QDPPMixer, R10: R7 body + 1024-thread workgroups + launch_bounds(1024,4).
// R9 postmortem: big WGs DID lift occupancy 30->58% (confirming the ~30% cap
// was WG-dispatch-granularity, not VGPR/LDS) but launch_bounds(1024,8) forced
// VGPR 64->32 and spilled (WRITE_SIZE 1.3->62MB = the whole regression).
// R10 keeps 16 waves/WG and relaxes the bound to 4 waves/EU (128 VGPR budget)
// so the body compiles spill-free at ~64 VGPR; 64 VGPR still allows 8 waves/
// SIMD hardware-side. Single-variable fix of R9's confound.

constexpr int   NA         = 8;
constexpr float Q_MIN      = -10.0f;
constexpr float Q_MAX      = 10.0f;
constexpr float NOISE_COEF = 0.1f;
constexpr float EPS        = 1e-8f;

typedef _Float16 half2_t __attribute__((ext_vector_type(2)));

__device__ __forceinline__ float dot2(half2_t a, half2_t b, float c) {
#if __has_builtin(__builtin_amdgcn_fdot2)
    return __builtin_amdgcn_fdot2(a, b, c, false);
#else
    return fmaf((float)a.x, (float)b.x, fmaf((float)a.y, (float)b.y, c));
#endif
}

// quad butterfly adds (pure VALU DPP)
__device__ __forceinline__ float qadd1(float x) {
    return x + __builtin_bit_cast(float,
        __builtin_amdgcn_mov_dpp(__builtin_bit_cast(int, x), 0xB1, 0xF, 0xF, true));
}
__device__ __forceinline__ float qadd2(float x) {
    return x + __builtin_bit_cast(float,
        __builtin_amdgcn_mov_dpp(__builtin_bit_cast(int, x), 0x4E, 0xF, 0xF, true));
}

// ---- convert W (8000x32 fp32) -> fp16, 4 floats/thread ----
__global__ __launch_bounds__(256) void convert_kernel(
    const float* __restrict__ W, __half* __restrict__ W16, int n4)
{
    int t = blockIdx.x * blockDim.x + threadIdx.x;
    if (t >= n4) return;
    float4 v = reinterpret_cast<const float4*>(W)[t];
    ushort4 h;
    h.x = __half_as_ushort(__float2half(v.x));
    h.y = __half_as_ushort(__float2half(v.y));
    h.z = __half_as_ushort(__float2half(v.z));
    h.w = __half_as_ushort(__float2half(v.w));
    reinterpret_cast<ushort4*>(W16)[t] = h;
}

__global__ __launch_bounds__(1024, 4) void qdpp_kernel(
    const float* __restrict__ agent_qs,
    const int*   __restrict__ states,
    const int*   __restrict__ actions,
    const float* __restrict__ noise,
    const __half* __restrict__ W16,   // (8000, 32) fp16, rows 64B
    float*       __restrict__ out,
    int bs)
{
    int tid = blockIdx.x * blockDim.x + threadIdx.x;
    int e = tid >> 2;        // element index (4 lanes per element)
    int l = tid & 3;         // lane in quad: halves [8l, 8l+8) of each row
    if (e >= bs) return;
    size_t base = (size_t)e * NA;

    // ---- indices (quad-broadcast loads) ----
    int4 s0 = *reinterpret_cast<const int4*>(states + base);
    int4 s1 = *reinterpret_cast<const int4*>(states + base + 4);
    int4 a0 = *reinterpret_cast<const int4*>(actions + base);
    int4 a1 = *reinterpret_cast<const int4*>(actions + base + 4);

    int lb = 8 * l;          // half-element offset within row
    int off[8];
    off[0] = (s0.x * 10 + a0.x        ) * 32 + lb;
    off[1] = (s0.y * 10 + a0.y + 1000 ) * 32 + lb;
    off[2] = (s0.z * 10 + a0.z + 2000 ) * 32 + lb;
    off[3] = (s0.w * 10 + a0.w + 3000 ) * 32 + lb;
    off[4] = (s1.x * 10 + a1.x + 4000 ) * 32 + lb;
    off[5] = (s1.y * 10 + a1.y + 5000 ) * 32 + lb;
    off[6] = (s1.z * 10 + a1.z + 6000 ) * 32 + lb;
    off[7] = (s1.w * 10 + a1.w + 7000 ) * 32 + lb;

    // ---- gather: ONE 16B instr per row; quad covers the whole 64B row ----
    uint4 raw[8];
    #pragma unroll
    for (int i = 0; i < 8; i++)
        raw[i] = *reinterpret_cast<const uint4*>(W16 + off[i]);

    // ---- streaming loads issued while gathers are in flight ----
    float4 qa = *reinterpret_cast<const float4*>(agent_qs + base);
    float4 qb = *reinterpret_cast<const float4*>(agent_qs + base + 4);
    float4 n0 = *reinterpret_cast<const float4*>(noise + base);
    float4 n1 = *reinterpret_cast<const float4*>(noise + base + 4);

    half2_t h[8][4];
    #pragma unroll
    for (int i = 0; i < 8; i++) {
        h[i][0] = __builtin_bit_cast(half2_t, raw[i].x);
        h[i][1] = __builtin_bit_cast(half2_t, raw[i].y);
        h[i][2] = __builtin_bit_cast(half2_t, raw[i].z);
        h[i][3] = __builtin_bit_cast(half2_t, raw[i].w);
    }

    // ---- per-lane partial Gram (this lane's 8 of 32 dims), v_dot2 chains ----
    float g[8][8];
    #pragma unroll
    for (int i = 0; i < 8; i++) {
        #pragma unroll
        for (int j = i; j < 8; j++) {
            float acc = dot2(h[i][0], h[j][0], 0.0f);
            acc = dot2(h[i][1], h[j][1], acc);
            acc = dot2(h[i][2], h[j][2], acc);
            acc = dot2(h[i][3], h[j][3], acc);
            g[i][j] = acc;
        }
    }

    // ---- quad butterfly reduce (pure VALU DPP) ----
    #pragma unroll
    for (int i = 0; i < 8; i++)
        #pragma unroll
        for (int j = i; j < 8; j++)
            g[i][j] = qadd2(qadd1(g[i][j]));

    // ---- Q-sum with clip ----
    float qsum = fminf(fmaxf(qa.x, Q_MIN), Q_MAX) + fminf(fmaxf(qa.y, Q_MIN), Q_MAX)
               + fminf(fmaxf(qa.z, Q_MIN), Q_MAX) + fminf(fmaxf(qa.w, Q_MIN), Q_MAX)
               + fminf(fmaxf(qb.x, Q_MIN), Q_MAX) + fminf(fmaxf(qb.y, Q_MIN), Q_MAX)
               + fminf(fmaxf(qb.z, Q_MIN), Q_MAX) + fminf(fmaxf(qb.w, Q_MIN), Q_MAX);

    float nz[8] = {n0.x, n0.y, n0.z, n0.w, n1.x, n1.y, n1.z, n1.w};

    // ---- Atil: off-diag = relu(g_ij), diag = g_ii*(1 + 0.1*nz_i + eps) ----
    float m[8][8];
    float pgii = 1.0f;
    #pragma unroll
    for (int i = 0; i < 8; i++) {
        pgii *= g[i][i];
        #pragma unroll
        for (int j = 0; j < 8; j++) {
            if (i == j) {
                m[i][i] = g[i][i] * fmaf(NOISE_COEF, nz[i], 1.0f + EPS);
            } else {
                float gij = (j > i) ? g[i][j] : g[j][i];   // compile-time select
                m[i][j] = fmaxf(gij, 0.0f);
            }
        }
    }

    // ---- det via unrolled no-pivot LU (diag-dominant in practice) ----
    float det = 1.0f;
    #pragma unroll
    for (int k = 0; k < 8; k++) {
        float p = m[k][k];
        det *= p;
        float ip = __builtin_amdgcn_rcpf(p);
        #pragma unroll
        for (int i = k + 1; i < 8; i++) {
            float f = m[i][k] * ip;
            #pragma unroll
            for (int j = k + 1; j < 8; j++)
                m[i][j] = fmaf(-f, m[k][j], m[i][j]);
        }
    }

    // det(M) = det(Atil)/prod(g_ii); out = qsum + log(det(M) + 1e-8)
    float detM = det * __builtin_amdgcn_rcpf(pgii);
    if (l == 0)
        out[e] = qsum + __logf(detM + EPS);
}

extern "C" void kernel_launch(void* const* d_in, const int* in_sizes, int n_in,
                              void* d_out, int out_size, void* d_ws, size_t ws_size,
                              hipStream_t stream) {
    const float* agent_qs = (const float*)d_in[0];
    const int*   states   = (const int*)d_in[1];
    const int*   actions  = (const int*)d_in[2];
    const float* noise    = (const float*)d_in[3];
    const float* W        = (const float*)d_in[4];
    float*       out      = (float*)d_out;
    __half*      W16      = (__half*)d_ws;          // 256000 halves = 512 KB

    int wn = in_sizes[4];             // 256000 floats
    int n4 = wn / 4;
    convert_kernel<<<(n4 + 255) / 256, 256, 0, stream>>>(W, W16, n4);

    int bs = in_sizes[0] / NA;            // 262144
    const int block = 1024;               // 16 waves per WG
    long long total = (long long)bs * 4;  // 4 lanes per element
    int grid = (int)((total + block - 1) / block);   // 1024 WGs
    qdpp_kernel<<<grid, block, 0, stream>>>(agent_qs, states, actions, noise, W16, out, bs);
}